// Round 1
// baseline (7540.144 us; speedup 1.0000x reference)
//
#include <hip/hip_runtime.h>
#include <cstddef>
#include <cstdint>

// ---------------------------------------------------------------------------
// Hyperbolic (Poincare-ball) entity-typing forward pass, MI355X / gfx950.
// All math f32; xg / GRU-states / ctx stored bf16 (activation-only, <=0.4% rel).
// Sizes: B=256 L=128 ML=8 CL=16 E=300 S=256 S2=512 D=1280 C=128.
// ---------------------------------------------------------------------------

#define EPS_  1e-15f
#define PMAX_ 0.99999f    // 1 - 1e-5

__device__ __forceinline__ float wred(float v){
#pragma unroll
  for (int o = 32; o; o >>= 1) v += __shfl_xor(v, o, 64);
  return v;
}
__device__ __forceinline__ float wredmax(float v){
#pragma unroll
  for (int o = 32; o; o >>= 1) v = fmaxf(v, __shfl_xor(v, o, 64));
  return v;
}
__device__ __forceinline__ float snorm(float s){ return sqrtf(fmaxf(s, EPS_)); }
__device__ __forceinline__ float clamp11(float x){
  return fminf(fmaxf(x, -1.f + 1e-7f), 1.f - 1e-7f);
}
__device__ __forceinline__ float bf2f(unsigned short u){
  union { unsigned int i; float f; } v; v.i = ((unsigned int)u) << 16; return v.f;
}
__device__ __forceinline__ unsigned short f2bf(float f){
  union { float f; unsigned int i; } v; v.f = f;
  unsigned int x = v.i;
  x += 0x7fffu + ((x >> 16) & 1u);   // RNE
  return (unsigned short)(x >> 16);
}

template<int N>
__device__ __forceinline__ float sq_part(const float* a){
  float s = 0.f;
#pragma unroll
  for (int i = 0; i < N; i++) s += a[i]*a[i];
  return s;
}
template<int N>
__device__ __forceinline__ float dot_part(const float* a, const float* b){
  float s = 0.f;
#pragma unroll
  for (int i = 0; i < N; i++) s += a[i]*b[i];
  return s;
}
// mobius_add given full-row scalars x2,y2,xy
template<int N>
__device__ __forceinline__ void madd_vec(const float* x, float x2, const float* y,
                                         float y2, float xy, float* o){
  const float c1 = 1.f + 2.f*xy + y2;
  const float c2 = 1.f - x2;
  const float inv = 1.f / fmaxf(1.f + 2.f*xy + x2*y2, EPS_);
#pragma unroll
  for (int i = 0; i < N; i++) o[i] = (c1*x[i] + c2*y[i]) * inv;
}
// mobius_matvec tail: v = mx (in place) -> project(tanh(mxn/xn*artanh(xn))*mx/mxn)
template<int N>
__device__ __forceinline__ void mt_project(float* v, float mxn2, float xn2, float* n2out){
  const float xn  = snorm(xn2);
  const float mxn = snorm(mxn2);
  const float t   = tanhf(mxn/xn * atanhf(clamp11(xn)));
  float sc = t/mxn;
  float n2 = sc*sc*mxn2;
  const float n = snorm(n2);
  if (n > PMAX_){ const float s = PMAX_/n; sc *= s; n2 *= s*s; }
#pragma unroll
  for (int i = 0; i < N; i++) v[i] *= sc;
  *n2out = n2;
}
template<int N>
__device__ __forceinline__ void project_vec(float* v, float* n2io){
  float n2 = *n2io;
  const float n = snorm(n2);
  if (n > PMAX_){
    const float s = PMAX_/n;
#pragma unroll
    for (int i = 0; i < N; i++) v[i] *= s;
    n2 *= s*s;
  }
  *n2io = n2;
}
// mobius_pw_mul(w, x) with xn2 = |x|^2 known
template<int N>
__device__ __forceinline__ void pwmul(const float* wv_, const float* x, float xn2,
                                      float* out, float* n2out){
  float s = 0.f;
#pragma unroll
  for (int i = 0; i < N; i++){ out[i] = wv_[i]*x[i]; s += out[i]*out[i]; }
  const float wxn2 = wred(s);
  const float xn  = snorm(xn2);
  const float wxn = snorm(wxn2);
  const float t = tanhf(wxn/xn * atanhf(clamp11(xn)));
  float sc = t/wxn;
  float n2 = sc*sc*wxn2;
  const float n = snorm(n2);
  if (n > PMAX_){ const float s2 = PMAX_/n; sc *= s2; n2 *= s2*s2; }
#pragma unroll
  for (int i = 0; i < N; i++) out[i] *= sc;
  *n2out = n2;
}

// ---------------------------------------------------------------------------
// Generic tiled f32 GEMM: C[M,N] = A[M,K] @ B[K,N].
// AMODE: 0 = f32 direct, 1 = f32 row-gathered via idx (A = lut), 2 = bf16 direct.
// M, N multiples of 128; K arbitrary (tail zero-filled).
// ---------------------------------------------------------------------------
template<int AMODE>
__global__ __launch_bounds__(256) void mm_kernel(const void* __restrict__ Aptr,
    const int* __restrict__ idx, const float* __restrict__ Bm,
    float* __restrict__ Cm, int M, int N, int K)
{
  __shared__ __align__(16) float As[8][128];
  __shared__ __align__(16) float Bs[8][132];
  const int tid = threadIdx.x;
  const int n0 = blockIdx.x * 128;
  const int m0 = blockIdx.y * 128;
  const int tr = tid >> 4, tc = tid & 15;
  const int sm = tid & 127, sk = (tid >> 7) * 4;
  const int bk = tid >> 5,  bn = (tid & 31) * 4;
  long arow;
  if constexpr (AMODE == 1) arow = (long)idx[m0 + sm] * K;
  else                      arow = (long)(m0 + sm) * K;
  float acc[8][8];
#pragma unroll
  for (int i = 0; i < 8; i++)
#pragma unroll
    for (int j = 0; j < 8; j++) acc[i][j] = 0.f;

  for (int k0 = 0; k0 < K; k0 += 8){
    float av[4], bv[4];
    if constexpr (AMODE == 2){
      const unsigned short* A = (const unsigned short*)Aptr;
      const ushort4 u = *reinterpret_cast<const ushort4*>(A + arow + k0 + sk);
      av[0]=bf2f(u.x); av[1]=bf2f(u.y); av[2]=bf2f(u.z); av[3]=bf2f(u.w);
    } else {
      const float* A = (const float*)Aptr;
      if (k0 + sk + 3 < K){
        const float4 f = *reinterpret_cast<const float4*>(A + arow + k0 + sk);
        av[0]=f.x; av[1]=f.y; av[2]=f.z; av[3]=f.w;
      } else {
#pragma unroll
        for (int i = 0; i < 4; i++){
          const int kk = k0 + sk + i;
          av[i] = (kk < K) ? A[arow + kk] : 0.f;
        }
      }
    }
    {
      const int kb = k0 + bk;
      if (kb < K){
        const float4 f = *reinterpret_cast<const float4*>(Bm + (long)kb*N + n0 + bn);
        bv[0]=f.x; bv[1]=f.y; bv[2]=f.z; bv[3]=f.w;
      } else { bv[0]=bv[1]=bv[2]=bv[3]=0.f; }
    }
    __syncthreads();
    As[sk+0][sm]=av[0]; As[sk+1][sm]=av[1]; As[sk+2][sm]=av[2]; As[sk+3][sm]=av[3];
    *reinterpret_cast<float4*>(&Bs[bk][bn]) = make_float4(bv[0],bv[1],bv[2],bv[3]);
    __syncthreads();
#pragma unroll
    for (int k = 0; k < 8; k++){
      float a[8], bb[8];
      *(float4*)&a[0]  = *(const float4*)&As[k][tr*8];
      *(float4*)&a[4]  = *(const float4*)&As[k][tr*8+4];
      *(float4*)&bb[0] = *(const float4*)&Bs[k][tc*8];
      *(float4*)&bb[4] = *(const float4*)&Bs[k][tc*8+4];
#pragma unroll
      for (int i = 0; i < 8; i++)
#pragma unroll
        for (int j = 0; j < 8; j++) acc[i][j] += a[i]*bb[j];
    }
  }
#pragma unroll
  for (int i = 0; i < 8; i++){
    const long row = m0 + tr*8 + i;
    *(float4*)(Cm + row*N + n0 + tc*8)     = make_float4(acc[i][0],acc[i][1],acc[i][2],acc[i][3]);
    *(float4*)(Cm + row*N + n0 + tc*8 + 4) = make_float4(acc[i][4],acc[i][5],acc[i][6],acc[i][7]);
  }
}

// ---------------------------------------------------------------------------
// 32x32 LDS-tiled transpose: dst[k*R + j] = src[j*Kc + k]
// ---------------------------------------------------------------------------
__global__ __launch_bounds__(256) void transpose_k(const float* __restrict__ src,
    float* __restrict__ dst, int R, int Kc)
{
  __shared__ float t[32][33];
  const int bx = blockIdx.x * 32;   // k dim
  const int by = blockIdx.y * 32;   // j dim
  const int tx = threadIdx.x & 31, ty = threadIdx.x >> 5;
#pragma unroll
  for (int i = 0; i < 32; i += 8){
    const int j = by + ty + i, k = bx + tx;
    t[ty+i][tx] = (j < R && k < Kc) ? src[(long)j*Kc + k] : 0.f;
  }
  __syncthreads();
#pragma unroll
  for (int i = 0; i < 32; i += 8){
    const int k = bx + ty + i, j = by + tx;
    if (k < Kc && j < R) dst[(long)k*R + j] = t[tx][ty+i];
  }
}

// build gather-index arrays: ctxidx[t*256+b]=context[b*128+t]; chidx[t*256+b]=mchars[b*16+t]
__global__ void build_idx(const int* __restrict__ context, const int* __restrict__ mchars,
                          int* __restrict__ ctxidx, int* __restrict__ chidx)
{
  const int tid = blockIdx.x*256 + threadIdx.x;
  if (tid < 32768){
    const int t = tid >> 8, b = tid & 255;
    ctxidx[tid] = context[b*128 + t];
  } else if (tid < 32768 + 4096){
    const int o = tid - 32768;
    const int t = o >> 8, b = o & 255;
    chidx[o] = mchars[b*16 + t];
  }
}

// out[r] = sum_k lut[idx[r]][k]^2   (one wave per row)
__global__ __launch_bounds__(256) void sqn_gather(const float* __restrict__ lut,
    const int* __restrict__ idx, int K, float* __restrict__ outp)
{
  const int wv = threadIdx.x >> 6, lane = threadIdx.x & 63;
  const int r = blockIdx.x*4 + wv;
  const float* row = lut + (long)idx[r]*K;
  float s = 0.f;
  for (int k = lane; k < K; k += 64) s += row[k]*row[k];
  s = wred(s);
  if (lane == 0) outp[r] = s;
}

// mobius_matvec tail transform applied per (row, gate); out bf16
__global__ __launch_bounds__(256) void xg_transform(const float* __restrict__ mx,
    const float* __restrict__ xsqn, unsigned short* __restrict__ outp, int G)
{
  const int wv = threadIdx.x >> 6, lane = threadIdx.x & 63;
  const int wg = blockIdx.x*4 + wv;
  const int row = wg / G, g = wg - row*G;
  const long base = (long)row*(G*256) + g*256;
  float M[4];
#pragma unroll
  for (int i = 0; i < 4; i++) M[i] = mx[base + i*64 + lane];
  const float mxn2 = wred(sq_part<4>(M));
  float pn2; mt_project<4>(M, mxn2, xsqn[row], &pn2);
#pragma unroll
  for (int i = 0; i < 4; i++) outp[base + i*64 + lane] = f2bf(M[i]);
}

// ---------------------------------------------------------------------------
// Mobius GRU: one wave per (dir, batch-row); zero inter-wave deps.
// xg rows (t*256+b), 768 = [r|h|z]. Weights WtHH[dir][k][g*256+j] (transposed).
// ---------------------------------------------------------------------------
__device__ __forceinline__ void gru_gate(const float a[4], float hn2, const float xg_[4],
    const float bv[4], float b2, float out[4])
{
  float p[4];
#pragma unroll
  for (int i = 0; i < 4; i++) p[i] = a[i];
  const float mxn2 = wred(sq_part<4>(p));
  float pn2; mt_project<4>(p, mxn2, hn2, &pn2);
  const float y2 = wred(sq_part<4>(xg_));
  const float xy = wred(dot_part<4>(p, xg_));
  float m1[4]; madd_vec<4>(p, pn2, xg_, y2, xy, m1);
  const float m1n2 = wred(sq_part<4>(m1));
  const float xyb = wred(dot_part<4>(m1, bv));
  float m2[4]; madd_vec<4>(m1, m1n2, bv, b2, xyb, m2);
  const float m2n2 = wred(sq_part<4>(m2));
  const float n = snorm(m2n2);
  const float fac = atanhf(clamp11(n)) / n;
#pragma unroll
  for (int i = 0; i < 4; i++) out[i] = 1.f/(1.f + expf(-fac*m2[i]));
}

__global__ __launch_bounds__(256) void gru_kernel(
    const unsigned short* __restrict__ xg,     // [2][32768][768] bf16
    const float* __restrict__ WtHH,            // [2][256][768]
    const float* __restrict__ bias_f, const float* __restrict__ bias_b, // [3][256]
    unsigned short* __restrict__ states_f, unsigned short* __restrict__ states_b) // [B*L][256]
{
  const int bid = blockIdx.x;                  // 0..127
  const int dir = bid >> 6;
  const int wv = threadIdx.x >> 6, lane = threadIdx.x & 63;
  const int b = ((bid & 63) << 2) + wv;
  const int j0 = lane << 2;
  const float* Wt = WtHH + (long)dir * (256*768);
  const unsigned short* xgd = xg + (long)dir * 32768 * 768;
  const float* bias = dir ? bias_b : bias_f;
  unsigned short* states = dir ? states_b : states_f;
  __shared__ __align__(16) float hs[4][256];
  __shared__ __align__(16) float rhs[4][256];
  float h[4] = {0.f,0.f,0.f,0.f};
  float hn2 = 0.f;
#pragma unroll
  for (int i = 0; i < 4; i++) hs[wv][j0+i] = 0.f;
  float br[4], bh[4], bz[4];
#pragma unroll
  for (int i = 0; i < 4; i++){
    br[i] = bias[      j0+i];
    bh[i] = bias[256 + j0+i];
    bz[i] = bias[512 + j0+i];
  }
  const float br2 = wred(sq_part<4>(br));
  const float bh2 = wred(sq_part<4>(bh));
  const float bz2 = wred(sq_part<4>(bz));

  for (int t = 0; t < 128; t++){
    __syncthreads();   // keep waves in lockstep for L1 weight-stream reuse
    const int rx = (dir ? (127 - t) : t)*256 + b;
    const unsigned short* xr = xgd + (long)rx*768;
    float xgr[4], xgh[4], xgz[4];
    { const ushort4 u = *(const ushort4*)(xr + j0);       xgr[0]=bf2f(u.x); xgr[1]=bf2f(u.y); xgr[2]=bf2f(u.z); xgr[3]=bf2f(u.w); }
    { const ushort4 u = *(const ushort4*)(xr + 256 + j0); xgh[0]=bf2f(u.x); xgh[1]=bf2f(u.y); xgh[2]=bf2f(u.z); xgh[3]=bf2f(u.w); }
    { const ushort4 u = *(const ushort4*)(xr + 512 + j0); xgz[0]=bf2f(u.x); xgz[1]=bf2f(u.y); xgz[2]=bf2f(u.z); xgz[3]=bf2f(u.w); }

    // phase 1: az = h @ W_hz^T, ar = h @ W_hr^T  (z cols 512.., r cols 0..)
    float az[4]={0.f,0.f,0.f,0.f}, ar[4]={0.f,0.f,0.f,0.f};
    {
      const float* Wr_ = Wt + j0;
      const float* Wz_ = Wt + 512 + j0;
#pragma unroll 2
      for (int k0 = 0; k0 < 256; k0 += 4){
        const float4 hk = *(const float4*)&hs[wv][k0];
#pragma unroll
        for (int kk = 0; kk < 4; kk++){
          const float hv = (&hk.x)[kk];
          const float4 wz4 = *(const float4*)(Wz_ + (long)(k0+kk)*768);
          const float4 wr4 = *(const float4*)(Wr_ + (long)(k0+kk)*768);
          az[0] += hv*wz4.x; az[1] += hv*wz4.y; az[2] += hv*wz4.z; az[3] += hv*wz4.w;
          ar[0] += hv*wr4.x; ar[1] += hv*wr4.y; ar[2] += hv*wr4.z; ar[3] += hv*wr4.w;
        }
      }
    }
    float z[4], r[4];
    gru_gate(az, hn2, xgz, bz, bz2, z);
    gru_gate(ar, hn2, xgr, br, br2, r);
    float rh[4], rhn2;
    pwmul<4>(r, h, hn2, rh, &rhn2);
    *(float4*)&rhs[wv][j0] = make_float4(rh[0],rh[1],rh[2],rh[3]);
    __syncthreads();
    // phase 2: ah = rh @ W_hhh^T  (cols 256..)
    float ah[4]={0.f,0.f,0.f,0.f};
    {
      const float* Wh_ = Wt + 256 + j0;
#pragma unroll 2
      for (int k0 = 0; k0 < 256; k0 += 4){
        const float4 hk = *(const float4*)&rhs[wv][k0];
#pragma unroll
        for (int kk = 0; kk < 4; kk++){
          const float hv = (&hk.x)[kk];
          const float4 w4 = *(const float4*)(Wh_ + (long)(k0+kk)*768);
          ah[0] += hv*w4.x; ah[1] += hv*w4.y; ah[2] += hv*w4.z; ah[3] += hv*w4.w;
        }
      }
    }
    // h_tilde = madd(madd(mt(ah), xgh), bh)
    const float mxn2 = wred(sq_part<4>(ah));
    float pn2; mt_project<4>(ah, mxn2, rhn2, &pn2);
    const float y2  = wred(sq_part<4>(xgh));
    const float xy  = wred(dot_part<4>(ah, xgh));
    float m1[4]; madd_vec<4>(ah, pn2, xgh, y2, xy, m1);
    const float m1n2 = wred(sq_part<4>(m1));
    const float xyb  = wred(dot_part<4>(m1, bh));
    float ht[4]; madd_vec<4>(m1, m1n2, bh, bh2, xyb, ht);
    const float htn2 = wred(sq_part<4>(ht));
    // delta = madd(-h, ht)
    float nh[4];
#pragma unroll
    for (int i = 0; i < 4; i++) nh[i] = -h[i];
    const float xyd = wred(dot_part<4>(nh, ht));
    float dl[4]; madd_vec<4>(nh, hn2, ht, htn2, xyd, dl);
    const float dln2 = wred(sq_part<4>(dl));
    float pw[4], pwn2;
    pwmul<4>(z, dl, dln2, pw, &pwn2);
    const float xyh = wred(dot_part<4>(h, pw));
    float hnew[4]; madd_vec<4>(h, hn2, pw, pwn2, xyh, hnew);
#pragma unroll
    for (int i = 0; i < 4; i++) h[i] = hnew[i];
    hn2 = wred(sq_part<4>(h));
    *(float4*)&hs[wv][j0] = make_float4(h[0],h[1],h[2],h[3]);
    const int l = dir ? (127 - t) : t;
    unsigned short* srow = states + ((long)b*128 + l)*256 + j0;
    ushort4 su; su.x=f2bf(h[0]); su.y=f2bf(h[1]); su.z=f2bf(h[2]); su.w=f2bf(h[3]);
    *(ushort4*)srow = su;
  }
}

// ---------------------------------------------------------------------------
// Char Mobius-RNN: h = project(madd(madd(matvec(h, W), xg), b)), 16 steps.
// ---------------------------------------------------------------------------
__global__ __launch_bounds__(256) void char_rnn(
    const unsigned short* __restrict__ xgc,   // [16*256][256] rows t*256+b, bf16
    const float* __restrict__ Wc,             // [256][256] row-major (k,j)
    const float* __restrict__ cb,             // [256]
    float* __restrict__ cstates)              // [256*16][256] rows b*16+t
{
  const int wv = threadIdx.x >> 6, lane = threadIdx.x & 63;
  const int b = blockIdx.x*4 + wv;
  const int j0 = lane << 2;
  __shared__ __align__(16) float hs[4][256];
  float h[4] = {0.f,0.f,0.f,0.f};
  float hn2 = 0.f;
#pragma unroll
  for (int i = 0; i < 4; i++) hs[wv][j0+i] = 0.f;
  float cbv[4];
#pragma unroll
  for (int i = 0; i < 4; i++) cbv[i] = cb[j0+i];
  const float cb2 = wred(sq_part<4>(cbv));
  for (int t = 0; t < 16; t++){
    __syncthreads();
    const unsigned short* xr = xgc + ((long)t*256 + b)*256;
    float xgv[4];
    { const ushort4 u = *(const ushort4*)(xr + j0); xgv[0]=bf2f(u.x); xgv[1]=bf2f(u.y); xgv[2]=bf2f(u.z); xgv[3]=bf2f(u.w); }
    float a[4]={0.f,0.f,0.f,0.f};
#pragma unroll 2
    for (int k0 = 0; k0 < 256; k0 += 4){
      const float4 hk = *(const float4*)&hs[wv][k0];
#pragma unroll
      for (int kk = 0; kk < 4; kk++){
        const float hv = (&hk.x)[kk];
        const float4 w4 = *(const float4*)(Wc + (long)(k0+kk)*256 + j0);
        a[0] += hv*w4.x; a[1] += hv*w4.y; a[2] += hv*w4.z; a[3] += hv*w4.w;
      }
    }
    const float mxn2 = wred(sq_part<4>(a));
    float pn2; mt_project<4>(a, mxn2, hn2, &pn2);
    const float y2 = wred(sq_part<4>(xgv));
    const float xy = wred(dot_part<4>(a, xgv));
    float m1[4]; madd_vec<4>(a, pn2, xgv, y2, xy, m1);
    const float m1n2 = wred(sq_part<4>(m1));
    const float xyb  = wred(dot_part<4>(m1, cbv));
    float m2[4]; madd_vec<4>(m1, m1n2, cbv, cb2, xyb, m2);
    float m2n2 = wred(sq_part<4>(m2));
    project_vec<4>(m2, &m2n2);
#pragma unroll
    for (int i = 0; i < 4; i++) h[i] = m2[i];
    hn2 = m2n2;
    *(float4*)&hs[wv][j0] = make_float4(h[0],h[1],h[2],h[3]);
    *(float4*)(cstates + ((long)b*16 + t)*256 + j0) = make_float4(h[0],h[1],h[2],h[3]);
  }
}

// ---------------------------------------------------------------------------
// cc concat: ctx = project(madd(madd(mt(mxa,|sf|), mt(mxb,|sb|)), cc_bias)), bf16 out
// ---------------------------------------------------------------------------
__global__ __launch_bounds__(256) void cc_rowwise(const unsigned short* __restrict__ sf,
    const unsigned short* __restrict__ sb, const float* __restrict__ mxa,
    const float* __restrict__ mxb, const float* __restrict__ ccb,
    unsigned short* __restrict__ ctxo, int rowoff)
{
  const int wv = threadIdx.x >> 6, lane = threadIdx.x & 63;
  const int rloc = blockIdx.x*4 + wv;
  const long r = rowoff + rloc;
  float s = 0.f;
#pragma unroll
  for (int i = 0; i < 4; i++){ const float v = bf2f(sf[r*256 + i*64+lane]); s += v*v; }
  const float sfn2 = wred(s);
  s = 0.f;
#pragma unroll
  for (int i = 0; i < 4; i++){ const float v = bf2f(sb[r*256 + i*64+lane]); s += v*v; }
  const float sbn2 = wred(s);
  float A[8], Bv[8];
#pragma unroll
  for (int i = 0; i < 8; i++){ A[i]  = mxa[(long)rloc*512 + i*64+lane];
                               Bv[i] = mxb[(long)rloc*512 + i*64+lane]; }
  float pan2, pbn2;
  { const float n2 = wred(sq_part<8>(A));  mt_project<8>(A,  n2, sfn2, &pan2); }
  { const float n2 = wred(sq_part<8>(Bv)); mt_project<8>(Bv, n2, sbn2, &pbn2); }
  const float xy = wred(dot_part<8>(A, Bv));
  float M1[8]; madd_vec<8>(A, pan2, Bv, pbn2, xy, M1);
  const float m1n2 = wred(sq_part<8>(M1));
  float Cb[8];
#pragma unroll
  for (int i = 0; i < 8; i++) Cb[i] = ccb[i*64+lane];
  const float cb2 = wred(sq_part<8>(Cb));
  const float xyb = wred(dot_part<8>(M1, Cb));
  float M2[8]; madd_vec<8>(M1, m1n2, Cb, cb2, xyb, M2);
  float m2n2 = wred(sq_part<8>(M2));
  project_vec<8>(M2, &m2n2);
#pragma unroll
  for (int i = 0; i < 8; i++) ctxo[r*512 + i*64+lane] = f2bf(M2[i]);
}

// attn_emb = madd(ctx(bf16), pe) -> f32 + sqn
__global__ __launch_bounds__(256) void attn_add(const unsigned short* __restrict__ ctxv,
    const int* __restrict__ pos, const float* __restrict__ pet,
    float* __restrict__ oemb, float* __restrict__ osqn)
{
  const int wv = threadIdx.x >> 6, lane = threadIdx.x & 63;
  const long r = blockIdx.x*4 + wv;
  float X[8];
#pragma unroll
  for (int i = 0; i < 8; i++) X[i] = bf2f(ctxv[r*512 + i*64+lane]);
  const float x2 = wred(sq_part<8>(X));
  const int p = pos[r];
  float Y[8];
#pragma unroll
  for (int i = 0; i < 8; i++) Y[i] = pet[(long)p*512 + i*64+lane];
  const float y2 = wred(sq_part<8>(Y));
  const float xy = wred(dot_part<8>(X, Y));
  float O[8]; madd_vec<8>(X, x2, Y, y2, xy, O);
#pragma unroll
  for (int i = 0; i < 8; i++) oemb[r*512 + i*64+lane] = O[i];
  const float on2 = wred(sq_part<8>(O));
  if (lane == 0) osqn[r] = on2;
}

// mention variant: pos_idx = mentions>0 ? i+1 : 0 ; values f32
__global__ __launch_bounds__(256) void attn_add_m(const float* __restrict__ mvv,
    const int* __restrict__ mentions, const float* __restrict__ pet,
    float* __restrict__ oemb, float* __restrict__ osqn)
{
  const int wv = threadIdx.x >> 6, lane = threadIdx.x & 63;
  const long r = blockIdx.x*4 + wv;
  float X[8];
#pragma unroll
  for (int i = 0; i < 8; i++) X[i] = mvv[r*512 + i*64+lane];
  const float x2 = wred(sq_part<8>(X));
  const int men = mentions[r];
  const int p = (men > 0) ? (int)(r & 7) + 1 : 0;
  float Y[8];
#pragma unroll
  for (int i = 0; i < 8; i++) Y[i] = pet[(long)p*512 + i*64+lane];
  const float y2 = wred(sq_part<8>(Y));
  const float xy = wred(dot_part<8>(X, Y));
  float O[8]; madd_vec<8>(X, x2, Y, y2, xy, O);
#pragma unroll
  for (int i = 0; i < 8; i++) oemb[r*512 + i*64+lane] = O[i];
  const float on2 = wred(sq_part<8>(O));
  if (lane == 0) osqn[r] = on2;
}

// q = project(madd(mt(mxq,|emb|), bq)); k likewise; d = 2*artanh(|madd(-q,k)|)
__global__ __launch_bounds__(256) void qk_pdist(const float* __restrict__ mxq,
    const float* __restrict__ mxk, const float* __restrict__ sqn,
    const float* __restrict__ bq, const float* __restrict__ bk,
    float* __restrict__ dout)
{
  const int wv = threadIdx.x >> 6, lane = threadIdx.x & 63;
  const int r = blockIdx.x*4 + wv;
  const float xn2 = sqn[r];
  float Q[8];
#pragma unroll
  for (int i = 0; i < 8; i++) Q[i] = mxq[(long)r*512 + i*64+lane];
  { const float n2 = wred(sq_part<8>(Q)); float pn2; mt_project<8>(Q, n2, xn2, &pn2);
    float Bq[8];
#pragma unroll
    for (int i = 0; i < 8; i++) Bq[i] = bq[i*64+lane];
    const float b2 = wred(sq_part<8>(Bq));
    const float xy = wred(dot_part<8>(Q, Bq));
    float O[8]; madd_vec<8>(Q, pn2, Bq, b2, xy, O);
#pragma unroll
    for (int i = 0; i < 8; i++) Q[i] = O[i];
  }
  float qn2 = wred(sq_part<8>(Q));
  project_vec<8>(Q, &qn2);
  float Kv[8];
#pragma unroll
  for (int i = 0; i < 8; i++) Kv[i] = mxk[(long)r*512 + i*64+lane];
  { const float n2 = wred(sq_part<8>(Kv)); float pn2; mt_project<8>(Kv, n2, xn2, &pn2);
    float Bk[8];
#pragma unroll
    for (int i = 0; i < 8; i++) Bk[i] = bk[i*64+lane];
    const float b2 = wred(sq_part<8>(Bk));
    const float xy = wred(dot_part<8>(Kv, Bk));
    float O[8]; madd_vec<8>(Kv, pn2, Bk, b2, xy, O);
#pragma unroll
    for (int i = 0; i < 8; i++) Kv[i] = O[i];
  }
  float kn2 = wred(sq_part<8>(Kv));
  project_vec<8>(Kv, &kn2);
  float NQ[8];
#pragma unroll
  for (int i = 0; i < 8; i++) NQ[i] = -Q[i];
  const float xy = wred(dot_part<8>(NQ, Kv));
  float Z[8]; madd_vec<8>(NQ, qn2, Kv, kn2, xy, Z);
  const float zn2 = wred(sq_part<8>(Z));
  const float d = 2.f * atanhf(clamp11(snorm(zn2)));
  if (lane == 0) dout[r] = d;
}

__global__ __launch_bounds__(256) void softmax128(const float* __restrict__ d,
    const float* __restrict__ beta, float* __restrict__ w)
{
  const int wv = threadIdx.x >> 6, lane = threadIdx.x & 63;
  const int b = blockIdx.x*4 + wv;
  const float bt = beta[0];
  const float x0 = -bt * d[b*128 + lane];
  const float x1 = -bt * d[b*128 + 64 + lane];
  const float m = wredmax(fmaxf(x0, x1));
  const float e0 = expf(x0 - m), e1 = expf(x1 - m);
  const float s = wred(e0 + e1);
  w[b*128 + lane]      = e0 / s;
  w[b*128 + 64 + lane] = e1 / s;
}

__global__ void softmax8(const float* __restrict__ d, const float* __restrict__ beta,
                         float* __restrict__ w)
{
  const int b = threadIdx.x;   // 256
  const float bt = beta[0];
  float x[8]; float m = -1e30f;
#pragma unroll
  for (int i = 0; i < 8; i++){ x[i] = -bt * d[b*8+i]; m = fmaxf(m, x[i]); }
  float s = 0.f;
#pragma unroll
  for (int i = 0; i < 8; i++){ x[i] = expf(x[i]-m); s += x[i]; }
#pragma unroll
  for (int i = 0; i < 8; i++) w[b*8+i] = x[i] / s;
}

// weighted gyromidpoint via Klein model; one wave per batch row
template<int NPL, bool BF16V, bool HASW>
__global__ __launch_bounds__(256) void midpoint_kernel(const void* __restrict__ vals,
    const float* __restrict__ wts, float* __restrict__ outp, int Lseq)
{
  const int wv = threadIdx.x >> 6, lane = threadIdx.x & 63;
  const int b = blockIdx.x*4 + wv;
  const int D = NPL*64;
  float num[NPL];
#pragma unroll
  for (int i = 0; i < NPL; i++) num[i] = 0.f;
  float den = 0.f;
  for (int l = 0; l < Lseq; l++){
    const long base = ((long)b*Lseq + l)*D;
    float v[NPL]; float s = 0.f;
#pragma unroll
    for (int i = 0; i < NPL; i++){
      v[i] = BF16V ? bf2f(((const unsigned short*)vals)[base + i*64+lane])
                   : ((const float*)vals)[base + i*64+lane];
      s += v[i]*v[i];
    }
    const float v2 = wred(s);
    const float f = 2.f/(1.f + v2);          // klein = f*v
    const float kl2 = v2*f*f;
    const float gamma = 1.f/sqrtf(fmaxf(1.f - kl2, EPS_));
    const float wgt = HASW ? wts[b*Lseq + l] : 1.f;
    const float wg = wgt*gamma;
#pragma unroll
    for (int i = 0; i < NPL; i++) num[i] += wg*(f*v[i]);
    den += wg;
  }
  den = fmaxf(den, EPS_);
  float x[NPL]; float s = 0.f;
#pragma unroll
  for (int i = 0; i < NPL; i++){ x[i] = num[i]/den; s += x[i]*x[i]; }
  const float k2 = wred(s);
  const float inv = 1.f/(1.f + sqrtf(fmaxf(1.f - k2, EPS_)));
#pragma unroll
  for (int i = 0; i < NPL; i++) outp[(long)b*D + i*64+lane] = x[i]*inv;
}

// mention w2s mobius_linear with tanh nonlinearity
__global__ __launch_bounds__(256) void mv_rowwise(const float* __restrict__ mx,
    const float* __restrict__ xsqn, const float* __restrict__ bb, float* __restrict__ outp)
{
  const int wv = threadIdx.x >> 6, lane = threadIdx.x & 63;
  const long r = blockIdx.x*4 + wv;
  float M[8];
#pragma unroll
  for (int i = 0; i < 8; i++) M[i] = mx[r*512 + i*64+lane];
  { const float n2 = wred(sq_part<8>(M)); float pn2; mt_project<8>(M, n2, xsqn[r], &pn2);
    float Bv[8];
#pragma unroll
    for (int i = 0; i < 8; i++) Bv[i] = bb[i*64+lane];
    const float b2 = wred(sq_part<8>(Bv));
    const float xy = wred(dot_part<8>(M, Bv));
    float O[8]; madd_vec<8>(M, pn2, Bv, b2, xy, O);
#pragma unroll
    for (int i = 0; i < 8; i++) M[i] = O[i];
  }
  float on2 = wred(sq_part<8>(M));
  project_vec<8>(M, &on2);
  // nonlin: project(expmap0(tanh(logmap0(M))))
  { const float n = snorm(on2);
    const float fac = atanhf(clamp11(n))/n;
#pragma unroll
    for (int i = 0; i < 8; i++) M[i] = tanhf(fac*M[i]); }
  const float un2 = wred(sq_part<8>(M));
  { const float n = snorm(un2);
    const float fac = tanhf(n)/n;
    float en2 = fac*fac*un2;
#pragma unroll
    for (int i = 0; i < 8; i++) M[i] *= fac;
    project_vec<8>(M, &en2); }
#pragma unroll
  for (int i = 0; i < 8; i++) outp[r*512 + i*64+lane] = M[i];
}

// joint = project(madd(madd(madd(mt(jm),mt(jc)),mt(jch)),fc_bias))
__global__ __launch_bounds__(256) void final_rowwise(const float* __restrict__ jm,
    const float* __restrict__ jc, const float* __restrict__ jch,
    const float* __restrict__ mvec, const float* __restrict__ cvec,
    const float* __restrict__ chvec, const float* __restrict__ fcb,
    float* __restrict__ joint)
{
  const int wv = threadIdx.x >> 6, lane = threadIdx.x & 63;
  const long b = blockIdx.x*4 + wv;
  float s;
  s = 0.f; for (int i = 0; i < 8; i++){ const float v = mvec[b*512 + i*64+lane]; s += v*v; }
  const float mn2 = wred(s);
  s = 0.f; for (int i = 0; i < 8; i++){ const float v = cvec[b*512 + i*64+lane]; s += v*v; }
  const float cn2 = wred(s);
  s = 0.f; for (int i = 0; i < 4; i++){ const float v = chvec[b*256 + i*64+lane]; s += v*v; }
  const float chn2 = wred(s);
  float A[20];
#pragma unroll
  for (int i = 0; i < 20; i++) A[i] = jm[b*1280 + i*64+lane];
  float an2;
  { const float n2 = wred(sq_part<20>(A)); mt_project<20>(A, n2, mn2, &an2); }
  float T[20];
#pragma unroll
  for (int i = 0; i < 20; i++) T[i] = jc[b*1280 + i*64+lane];
  float tn2;
  { const float n2 = wred(sq_part<20>(T)); mt_project<20>(T, n2, cn2, &tn2); }
  { const float xy = wred(dot_part<20>(A, T));
    float O[20]; madd_vec<20>(A, an2, T, tn2, xy, O);
#pragma unroll
    for (int i = 0; i < 20; i++) A[i] = O[i];
    an2 = wred(sq_part<20>(A)); }
#pragma unroll
  for (int i = 0; i < 20; i++) T[i] = jch[b*1280 + i*64+lane];
  { const float n2 = wred(sq_part<20>(T)); mt_project<20>(T, n2, chn2, &tn2); }
  { const float xy = wred(dot_part<20>(A, T));
    float O[20]; madd_vec<20>(A, an2, T, tn2, xy, O);
#pragma unroll
    for (int i = 0; i < 20; i++) A[i] = O[i];
    an2 = wred(sq_part<20>(A)); }
#pragma unroll
  for (int i = 0; i < 20; i++) T[i] = fcb[i*64+lane];
  tn2 = wred(sq_part<20>(T));
  { const float xy = wred(dot_part<20>(A, T));
    float O[20]; madd_vec<20>(A, an2, T, tn2, xy, O);
#pragma unroll
    for (int i = 0; i < 20; i++) A[i] = O[i];
    an2 = wred(sq_part<20>(A)); }
  project_vec<20>(A, &an2);
#pragma unroll
  for (int i = 0; i < 20; i++) joint[b*1280 + i*64+lane] = A[i];
}

// hyperbolic MLR head: out[b,c] = 2*a_n*asinh(2<z,a> / (clip(1-|z|^2)*a_n))
__global__ __launch_bounds__(256) void mlr_kernel(const float* __restrict__ joint,
    const float* __restrict__ P, const float* __restrict__ A, float* __restrict__ outp)
{
  const int wv = threadIdx.x >> 6, lane = threadIdx.x & 63;
  const int pair = blockIdx.x*4 + wv;
  const long b = pair >> 7, c = pair & 127;
  float Pv[20], J[20];
#pragma unroll
  for (int i = 0; i < 20; i++){
    Pv[i] = -P[c*1280 + i*64+lane];
    J[i]  = joint[b*1280 + i*64+lane];
  }
  const float p2 = wred(sq_part<20>(Pv));
  const float j2 = wred(sq_part<20>(J));
  const float xy = wred(dot_part<20>(Pv, J));
  float Z[20]; madd_vec<20>(Pv, p2, J, j2, xy, Z);
  float sza = 0.f, sz2 = 0.f, sa2 = 0.f;
#pragma unroll
  for (int i = 0; i < 20; i++){
    const float a = A[c*1280 + i*64+lane];
    sza += Z[i]*a; sz2 += Z[i]*Z[i]; sa2 += a*a;
  }
  const float za = wred(sza), z2 = wred(sz2), a2 = wred(sa2);
  const float an = sqrtf(fmaxf(a2, EPS_));
  const float v = 2.f*za / (fmaxf(1.f - z2, EPS_)*an);
  if (lane == 0) outp[pair] = 2.f*an*asinhf(v);
}

// ---------------------------------------------------------------------------
extern "C" void kernel_launch(void* const* d_in, const int* in_sizes, int n_in,
                              void* d_out, int out_size, void* d_ws, size_t ws_size,
                              hipStream_t stream)
{
  (void)in_sizes; (void)n_in; (void)out_size;
  const int*   context   = (const int*)  d_in[0];
  const int*   ctx_position=(const int*) d_in[1];
  const int*   mentions  = (const int*)  d_in[2];
  const int*   mchars    = (const int*)  d_in[3];
  const float* word_lut  = (const float*)d_in[4];
  const float* char_lut  = (const float*)d_in[5];
  const float* gf_Wih    = (const float*)d_in[6];
  const float* gf_Whh    = (const float*)d_in[7];
  const float* gf_b      = (const float*)d_in[8];
  const float* gb_Wih    = (const float*)d_in[9];
  const float* gb_Whh    = (const float*)d_in[10];
  const float* gb_b      = (const float*)d_in[11];
  const float* w2s_W     = (const float*)d_in[12];
  const float* w2s_b     = (const float*)d_in[13];
  const float* men_pos   = (const float*)d_in[14];
  const float* men_Wq    = (const float*)d_in[15];
  const float* men_bq    = (const float*)d_in[16];
  const float* men_Wk    = (const float*)d_in[17];
  const float* men_bk    = (const float*)d_in[18];
  const float* men_beta  = (const float*)d_in[19];
  const float* char_W    = (const float*)d_in[20];
  const float* char_U    = (const float*)d_in[21];
  const float* char_b    = (const float*)d_in[22];
  const float* cc_Wa     = (const float*)d_in[23];
  const float* cc_Wb     = (const float*)d_in[24];
  const float* cc_bias   = (const float*)d_in[25];
  const float* ctx_pos_t = (const float*)d_in[26];
  const float* ctx_Wq    = (const float*)d_in[27];
  const float* ctx_bq    = (const float*)d_in[28];
  const float* ctx_Wk    = (const float*)d_in[29];
  const float* ctx_bk    = (const float*)d_in[30];
  const float* ctx_beta  = (const float*)d_in[31];
  const float* fc_Wm     = (const float*)d_in[32];
  const float* fc_Wc     = (const float*)d_in[33];
  const float* fc_Wch    = (const float*)d_in[34];
  const float* fc_bias   = (const float*)d_in[35];
  const float* mlr_p     = (const float*)d_in[36];
  const float* mlr_a     = (const float*)d_in[37];
  float* out = (float*)d_out;

  // ---- workspace bump allocator ----
  char* wsb = (char*)d_ws;
  size_t off = 0;
  auto alloc = [&](size_t bytes) -> void* {
    void* p = wsb + off;
    off += (bytes + 255) & ~(size_t)255;
    return p;
  };
  float* WtIH = (float*)alloc(2UL*300*768*4);     // [dir][k][j] = Wih[j][k]
  float* WtHH = (float*)alloc(2UL*256*768*4);     // [dir][k][j] = Whh[j][k]
  int*   ctxidx = (int*)alloc(32768UL*4);
  int*   chidx  = (int*)alloc(4096UL*4);
  float* xsqn   = (float*)alloc(32768UL*4);
  float* msqn   = (float*)alloc(2048UL*4);
  float* chsqn  = (float*)alloc(4096UL*4);
  unsigned short* xg = (unsigned short*)alloc(2UL*32768*768*2);   // bf16
  unsigned short* states_f = (unsigned short*)alloc(32768UL*256*2);
  unsigned short* states_b = (unsigned short*)alloc(32768UL*256*2);
  unsigned short* ctxv = (unsigned short*)alloc(32768UL*512*2);
  float* attn_sqn = (float*)alloc(32768UL*4);
  float* dctx = (float*)alloc(32768UL*4);
  float* wctx = (float*)alloc(32768UL*4);
  float* ctx_vec = (float*)alloc(256UL*512*4);
  float* mxbuf = (float*)alloc(2UL*8192*512*4);   // shared chunk scratch
  float* mv = (float*)alloc(2048UL*512*4);
  float* attn_embm = (float*)alloc(2048UL*512*4);
  float* amsqn = (float*)alloc(2048UL*4);
  float* dm = (float*)alloc(2048UL*4);
  float* wm = (float*)alloc(2048UL*4);
  float* mention_vec = (float*)alloc(256UL*512*4);
  unsigned short* xgc = (unsigned short*)alloc(4096UL*256*2);
  float* char_states = (float*)alloc(4096UL*256*4);
  float* char_vec = (float*)alloc(256UL*256*4);
  float* joint = (float*)alloc(256UL*1280*4);
  if (off > ws_size) return;                       // workspace too small: bail cleanly
  float* attn_embc = (float*)xg;                   // overlay: xg dead after GRU (67MB<=100MB)
  float* mxh0 = mxbuf;
  float* mxh1 = mxbuf + 8192UL*512;

  // ---- weight transposes ----
  transpose_k<<<dim3(10,24),256,0,stream>>>(gf_Wih, WtIH,            768, 300);
  transpose_k<<<dim3(10,24),256,0,stream>>>(gb_Wih, WtIH + 300*768,  768, 300);
  transpose_k<<<dim3(8,24), 256,0,stream>>>(gf_Whh, WtHH,            768, 256);
  transpose_k<<<dim3(8,24), 256,0,stream>>>(gb_Whh, WtHH + 256*768,  768, 256);

  // ---- gather indices + input sqn ----
  build_idx<<<144,256,0,stream>>>(context, mchars, ctxidx, chidx);
  sqn_gather<<<8192,256,0,stream>>>(word_lut, ctxidx, 300, xsqn);
  sqn_gather<<<512, 256,0,stream>>>(word_lut, mentions, 300, msqn);
  sqn_gather<<<1024,256,0,stream>>>(char_lut, chidx, 256, chsqn);

  // ---- GRU input precompute: xg[dir] = mobius_matvec(emb, Wih^T), bf16 ----
  for (int d2 = 0; d2 < 2; d2++){
    const float* wih_t = WtIH + (size_t)d2*300*768;
    for (int c = 0; c < 4; c++){
      mm_kernel<1><<<dim3(6,64),256,0,stream>>>(word_lut, ctxidx + c*8192, wih_t,
                                                mxbuf, 8192, 768, 300);
      xg_transform<<<6144,256,0,stream>>>(mxbuf, xsqn + c*8192,
          xg + ((size_t)d2*32768 + (size_t)c*8192)*768, 3);
    }
  }

  // ---- bidirectional Mobius GRU (single kernel, 128 steps) ----
  gru_kernel<<<128,256,0,stream>>>(xg, WtHH, gf_b, gb_b, states_f, states_b);

  // ---- mobius concat of directions -> ctx (bf16) ----
  for (int c = 0; c < 4; c++){
    mm_kernel<2><<<dim3(4,64),256,0,stream>>>(states_f + (size_t)c*8192*256, nullptr,
                                              cc_Wa, mxh0, 8192, 512, 256);
    mm_kernel<2><<<dim3(4,64),256,0,stream>>>(states_b + (size_t)c*8192*256, nullptr,
                                              cc_Wb, mxh1, 8192, 512, 256);
    cc_rowwise<<<2048,256,0,stream>>>(states_f, states_b, mxh0, mxh1, cc_bias,
                                      ctxv, c*8192);
  }

  // ---- context distance attention ----
  attn_add<<<8192,256,0,stream>>>(ctxv, ctx_position, ctx_pos_t, attn_embc, attn_sqn);
  for (int c = 0; c < 4; c++){
    mm_kernel<0><<<dim3(4,64),256,0,stream>>>(attn_embc + (size_t)c*8192*512, nullptr,
                                              ctx_Wq, mxh0, 8192, 512, 512);
    mm_kernel<0><<<dim3(4,64),256,0,stream>>>(attn_embc + (size_t)c*8192*512, nullptr,
                                              ctx_Wk, mxh1, 8192, 512, 512);
    qk_pdist<<<2048,256,0,stream>>>(mxh0, mxh1, attn_sqn + c*8192, ctx_bq, ctx_bk,
                                    dctx + c*8192);
  }
  softmax128<<<64,256,0,stream>>>(dctx, ctx_beta, wctx);
  midpoint_kernel<8,true,true><<<64,256,0,stream>>>(ctxv, wctx, ctx_vec, 128);

  // ---- mention encoder ----
  mm_kernel<1><<<dim3(4,16),256,0,stream>>>(word_lut, mentions, w2s_W, mxh0, 2048, 512, 300);
  mv_rowwise<<<512,256,0,stream>>>(mxh0, msqn, w2s_b, mv);
  attn_add_m<<<512,256,0,stream>>>(mv, mentions, men_pos, attn_embm, amsqn);
  mm_kernel<0><<<dim3(4,16),256,0,stream>>>(attn_embm, nullptr, men_Wq, mxh0, 2048, 512, 512);
  mm_kernel<0><<<dim3(4,16),256,0,stream>>>(attn_embm, nullptr, men_Wk, mxh1, 2048, 512, 512);
  qk_pdist<<<512,256,0,stream>>>(mxh0, mxh1, amsqn, men_bq, men_bk, dm);
  softmax8<<<1,256,0,stream>>>(dm, men_beta, wm);
  midpoint_kernel<8,false,true><<<64,256,0,stream>>>(mv, wm, mention_vec, 8);

  // ---- char encoder ----
  mm_kernel<1><<<dim3(2,32),256,0,stream>>>(char_lut, chidx, char_U, mxh0, 4096, 256, 256);
  xg_transform<<<1024,256,0,stream>>>(mxh0, chsqn, xgc, 1);
  char_rnn<<<64,256,0,stream>>>(xgc, char_W, char_b, char_states);
  midpoint_kernel<4,false,false><<<64,256,0,stream>>>(char_states, nullptr, char_vec, 16);

  // ---- full mobius concat + MLR ----
  float* jm = mxh0;
  float* jc = mxh0 + 256UL*1280;
  float* jch = mxh0 + 2UL*256*1280;
  mm_kernel<0><<<dim3(10,2),256,0,stream>>>(mention_vec, nullptr, fc_Wm, jm, 256, 1280, 512);
  mm_kernel<0><<<dim3(10,2),256,0,stream>>>(ctx_vec,     nullptr, fc_Wc, jc, 256, 1280, 512);
  mm_kernel<0><<<dim3(10,2),256,0,stream>>>(char_vec,    nullptr, fc_Wch, jch, 256, 1280, 256);
  final_rowwise<<<64,256,0,stream>>>(jm, jc, jch, mention_vec, ctx_vec, char_vec,
                                     fc_bias, joint);
  mlr_kernel<<<8192,256,0,stream>>>(joint, mlr_p, mlr_a, out);
}